// Round 1
// baseline (172.391 us; speedup 1.0000x reference)
//
#include <hip/hip_runtime.h>
#include <stdint.h>

#define N_UNITS   400
#define N_NEIGHB  64
#define C         3
#define S         2
#define T         10      // C + C*S + E, E=1
#define NSLICE    256     // kA blocks / PA slabs
#define HW_       (N_NEIGHB * N_UNITS / 2)   // 12800 packed words (4 u8 fields each)
#define NE_TOT    (N_NEIGHB * N_UNITS)       // 25600 (nb,u) entries
#define RGROUPS   4
#define SLAB_PER_G (NSLICE / RGROUPS)        // 64
#define BS        256
#define MB        1024    // k_main blocks

// ---------- JAX Threefry-2x32, key = (0, 1) (jax.random.key(1)) ----------
__device__ __forceinline__ uint32_t rotl32(uint32_t x, int d) {
    return (x << d) | (x >> (32 - d));
}

__device__ __forceinline__ void threefry_key01(uint32_t x0, uint32_t x1,
                                               uint32_t& o0, uint32_t& o1) {
    const uint32_t ks0 = 0u;
    const uint32_t ks1 = 1u;
    const uint32_t ks2 = 0x1BD11BDBu;  // 0x1BD11BDA ^ 0 ^ 1
    x0 += ks0; x1 += ks1;
#define TF_RND(r) { x0 += x1; x1 = rotl32(x1, r); x1 ^= x0; }
    TF_RND(13) TF_RND(15) TF_RND(26) TF_RND(6)
    x0 += ks1; x1 += ks2 + 1u;
    TF_RND(17) TF_RND(29) TF_RND(16) TF_RND(24)
    x0 += ks2; x1 += ks0 + 2u;
    TF_RND(13) TF_RND(15) TF_RND(26) TF_RND(6)
    x0 += ks0; x1 += ks1 + 3u;
    TF_RND(17) TF_RND(29) TF_RND(16) TF_RND(24)
    x0 += ks1; x1 += ks2 + 4u;
    TF_RND(13) TF_RND(15) TF_RND(26) TF_RND(6)
    x0 += ks2; x1 += ks0 + 5u;
#undef TF_RND
    o0 = x0; o1 = x1;
}

// jax_threefry_partitionable=True (default since jax 0.4.36):
// bits[i] = x0 ^ x1 of threefry2x32(key, (i >> 32, i & 0xffffffff)).
__device__ __forceinline__ int explore_index(int i, int ne) {
    uint32_t o0, o1;
    threefry_key01(0u, (uint32_t)i, o0, o1);
    uint32_t bits = o0 ^ o1;
    float u = __uint_as_float((bits >> 9) | 0x3F800000u) - 1.0f;
    int t = (int)floorf(u * (float)ne);
    return min(t, ne - 1);
}

// ---------- kA: single-pass full-64-nb partial histograms (u8 fields) -----
// entry e = nb*400+u; word = e>>1; lo/hi 16b half per e; within a half:
// bits 0-7 = h0 (top0 count), bits 8-15 = h12 (top1+top2 count).
// Per-slab counts are tiny (lambda ~0.3), so u8 cannot overflow.
__global__ void k_histA(const int* __restrict__ top,
                        const int* __restrict__ nbid,
                        uint32_t* __restrict__ PA, int n, int chunk) {
    __shared__ uint32_t hist[HW_];
    for (int k = threadIdx.x; k < HW_; k += blockDim.x) hist[k] = 0u;
    __syncthreads();
    int lo = blockIdx.x * chunk, hi = min(n, lo + chunk);
    const int4* top4 = (const int4*)top;
#define PROC(nb, t0, t1, t2) { \
    int b_ = (nb) * N_UNITS; \
    int e0 = b_ + (t0), e1 = b_ + (t1), e2 = b_ + (t2); \
    atomicAdd(&hist[e0 >> 1], 1u << ((e0 & 1) * 16)); \
    atomicAdd(&hist[e1 >> 1], 0x100u << ((e1 & 1) * 16)); \
    atomicAdd(&hist[e2 >> 1], 0x100u << ((e2 & 1) * 16)); }
    for (int i0 = lo + threadIdx.x * 4; i0 < hi; i0 += blockDim.x * 4) {
        if (i0 + 4 <= hi) {
            int4 nb4 = *(const int4*)(nbid + i0);
            int j = (i0 * 3) >> 2;
            int4 ta = top4[j], tb = top4[j + 1], tc = top4[j + 2];
            PROC(nb4.x, ta.x, ta.y, ta.z)
            PROC(nb4.y, ta.w, tb.x, tb.y)
            PROC(nb4.z, tb.z, tb.w, tc.x)
            PROC(nb4.w, tc.y, tc.z, tc.w)
        } else {
            for (int i = i0; i < hi; ++i)
                PROC(nbid[i], top[3 * i], top[3 * i + 1], top[3 * i + 2])
        }
    }
#undef PROC
    __syncthreads();
    uint32_t* Pb = PA + (size_t)blockIdx.x * HW_;
    for (int k = threadIdx.x; k < HW_; k += blockDim.x) Pb[k] = hist[k];
}

// ---------- kR: wide reduce of PA slabs into 4 packed partials ------------
// R4[g][e] = h0_sum (lo16) | h12_sum (hi16) over slab group g.
__global__ void k_reduceA(const uint32_t* __restrict__ PA,
                          uint32_t* __restrict__ R4) {
    int idx = blockIdx.x * blockDim.x + threadIdx.x;   // 0 .. 4*HW_-1
    int w = idx % HW_;
    int g = idx / HW_;
    uint32_t h0a = 0, h12a = 0, h0b = 0, h12b = 0;
    const uint32_t* p = PA + (size_t)g * SLAB_PER_G * HW_ + w;
#pragma unroll 8
    for (int s = 0; s < SLAB_PER_G; ++s) {
        uint32_t v = p[(size_t)s * HW_];
        h0a  += v & 0xFFu;
        h12a += (v >> 8) & 0xFFu;
        h0b  += (v >> 16) & 0xFFu;
        h12b += v >> 24;
    }
    uint32_t* o = R4 + (size_t)g * NE_TOT;
    o[2 * w]     = h0a | (h12a << 16);
    o[2 * w + 1] = h0b | (h12b << 16);
}

// ---------- kB: fused final reduce + tables + base counts -----------------
__global__ void k_tables_base(const uint32_t* __restrict__ R4,
                              const int* __restrict__ usn,
                              int* __restrict__ wtbl,
                              int* __restrict__ wne,
                              float* __restrict__ out_counts) {
    __shared__ int scan[512];
    __shared__ int s_c[N_UNITS];
    int b = blockIdx.x;          // neighborhood id
    int u = threadIdx.x;
    int h0 = 0, h3 = 0;
    if (u < N_UNITS) {
        int e = b * N_UNITS + u;
        // packed u16-field add: per-field totals << 65536, no cross-carry
        uint32_t tot = R4[e] + R4[NE_TOT + e] + R4[2 * NE_TOT + e]
                     + R4[3 * NE_TOT + e];
        h0 = (int)(tot & 0xFFFFu);
        h3 = h0 + (int)(tot >> 16);
        s_c[u] = h3;              // top0 + top1/top2 contributions
    }
    int p = (u < N_UNITS && h0 > 0) ? 1 : 0;
    scan[u] = p;
    __syncthreads();
    for (int off = 1; off < 512; off <<= 1) {
        int add = (u >= off) ? scan[u - off] : 0;
        __syncthreads();
        scan[u] += add;
        __syncthreads();
    }
    if (p) wtbl[b * N_UNITS + scan[u] - 1] = u;
    if (u == 511) wne[b] = scan[511];
    if (u < N_UNITS && h3 > 0) {
        int2 nbr = ((const int2*)usn)[u];
        atomicAdd(&s_c[nbr.x], h3);
        atomicAdd(&s_c[nbr.y], h3);
    }
    __syncthreads();
    if (u < N_UNITS)
        out_counts[u * N_NEIGHB + b] = (float)s_c[u];
}

// ---------- k_main: candidates + scores + explore counts (global atomic) --
// Per-256-spike tiles: int4-staged top loads; cand/scores staged in LDS and
// dumped dense with float4. Explore tail-count goes straight to out_counts
// (float atomicAdd; k_tables_base wrote base counts in the previous launch).
__global__ void k_main(const float* __restrict__ logliks,
                       const int* __restrict__ top,
                       const int* __restrict__ usn,
                       const int* __restrict__ nbid,
                       const int* __restrict__ wtbl,
                       const int* __restrict__ wne,
                       float* __restrict__ out_cand,
                       float* __restrict__ out_scores,
                       float* __restrict__ out_counts,
                       int n, int chunk) {
    __shared__ int   s_usn[N_UNITS * S];
    __shared__ float s_ll[N_UNITS];
    __shared__ int   s_ne[N_NEIGHB];
    __shared__ int   s_top[BS * 3];
    __shared__ float s_bc[BS * T];
    __shared__ float s_bs[BS * T];
    int tid = threadIdx.x;
    for (int k = tid; k < N_UNITS * S; k += BS) s_usn[k] = usn[k];
    for (int k = tid; k < N_UNITS; k += BS)     s_ll[k]  = logliks[k];
    for (int k = tid; k < N_NEIGHB; k += BS)    s_ne[k]  = wne[k];
    __syncthreads();

    int lo = blockIdx.x * chunk, hi = min(n, lo + chunk);
    for (int t0 = lo; t0 < hi; t0 += BS) {
        int cnt = min(BS, hi - t0);
        // stage this tile's top rows (t0 is 256-aligned -> int4-safe)
        if (cnt == BS) {
            if (tid < (BS * 3) / 4)
                ((int4*)s_top)[tid] = ((const int4*)(top + (size_t)t0 * 3))[tid];
        } else {
            for (int k = tid; k < cnt * 3; k += BS)
                s_top[k] = top[(size_t)t0 * 3 + k];
        }
        __syncthreads();   // also guarantees prior tile's dump is complete

        int i = t0 + tid;
        if (i < hi) {
            int nb = nbid[i];
            int cand[T];
            cand[0] = s_top[tid * 3 + 0];
            cand[1] = s_top[tid * 3 + 1];
            cand[2] = s_top[tid * 3 + 2];
#pragma unroll
            for (int c = 0; c < C; ++c) {
                cand[C + 2 * c]     = s_usn[cand[c] * 2 + 0];
                cand[C + 2 * c + 1] = s_usn[cand[c] * 2 + 1];
            }
            int ne = s_ne[nb];
            if (ne > 0) {
                int t = explore_index(i, ne);
                int ex = wtbl[nb * N_UNITS + t];
                cand[T - 1] = ex;
                // explore tail-count (pre-dup) straight into final counts
                atomicAdd(&out_counts[(size_t)ex * N_NEIGHB + nb], 1.0f);
            } else {
                cand[T - 1] = -1;
            }
#pragma unroll
            for (int jj = 0; jj < T; ++jj) {
                bool dup = false;
#pragma unroll
                for (int k = 0; k < jj; ++k) dup |= (cand[k] == cand[jj]);
                int v = dup ? -1 : cand[jj];   // reference erases dups to -1
                s_bc[tid * T + jj] = (float)v;
                s_bs[tid * T + jj] = (v >= 0) ? s_ll[v] : 0.0f;
            }
        }
        __syncthreads();

        // dense coalesced dump
        int nfloat = cnt * T;
        float* oc = out_cand   + (size_t)t0 * T;
        float* os = out_scores + (size_t)t0 * T;
        int nvec = nfloat & ~3;
        for (int e = tid * 4; e < nvec; e += BS * 4) {
            *(float4*)(oc + e) = *(const float4*)(s_bc + e);
            *(float4*)(os + e) = *(const float4*)(s_bs + e);
        }
        for (int e = nvec + tid; e < nfloat; e += BS) {
            oc[e] = s_bc[e];
            os[e] = s_bs[e];
        }
    }
}

extern "C" void kernel_launch(void* const* d_in, const int* in_sizes, int n_in,
                              void* d_out, int out_size, void* d_ws, size_t ws_size,
                              hipStream_t stream) {
    const float* logliks = (const float*)d_in[0];
    const int*   top     = (const int*)d_in[1];
    const int*   usn     = (const int*)d_in[2];
    const int*   nbid    = (const int*)d_in[3];

    int n = in_sizes[3];                                 // N_SPIKES
    int chunkA = ((n + NSLICE - 1) / NSLICE + 3) & ~3;   // mult of 4 (int4 path)
    int chunkM = (((n + MB - 1) / MB) + BS - 1) & ~(BS - 1);  // 256-aligned

    float* out        = (float*)d_out;
    float* out_cand   = out;
    float* out_counts = out + (size_t)n * T;
    float* out_scores = out_counts + (size_t)N_UNITS * N_NEIGHB;

    // Scratch in d_ws (~13.6 MB used):
    int*      wtbl = (int*)d_ws;                         // [64][400]
    int*      wne  = wtbl + N_NEIGHB * N_UNITS;          // [64]
    uint32_t* R4   = (uint32_t*)(wne + 64);              // 4*25600 = 409.6 KB
    uint32_t* PA   = R4 + (size_t)RGROUPS * NE_TOT;      // 256*12800 = 13.1 MB

    k_histA      <<<NSLICE, BS, 0, stream>>>(top, nbid, PA, n, chunkA);
    k_reduceA    <<<(RGROUPS * HW_) / BS, BS, 0, stream>>>(PA, R4);
    k_tables_base<<<N_NEIGHB, 512, 0, stream>>>(R4, usn, wtbl, wne, out_counts);
    k_main       <<<MB, BS, 0, stream>>>(logliks, top, usn, nbid, wtbl, wne,
                                         out_cand, out_scores, out_counts,
                                         n, chunkM);
}

// Round 2
// 155.001 us; speedup vs baseline: 1.1122x; 1.1122x over previous
//
#include <hip/hip_runtime.h>
#include <stdint.h>

#define N_UNITS   400
#define N_NEIGHB  64
#define C         3
#define S         2
#define T         10      // C + C*S + E, E=1
#define NSLICE    256     // kA blocks / PA slabs
#define HW_       (N_NEIGHB * N_UNITS / 2)   // 12800 packed words (4 u8 fields each)
#define NE_TOT    (N_NEIGHB * N_UNITS)       // 25600 (nb,u) entries
#define RGROUPS   4
#define SLAB_PER_G (NSLICE / RGROUPS)        // 64
#define BS        256
#define MCHUNK    1536                        // spikes per k_main block (6 tiles)
#define MB_MAX    ((1000000 + MCHUNK - 1) / MCHUNK)   // 651
#define EHW       (N_UNITS * 16)              // 6400 u8x4-packed explore words

// ---------- JAX Threefry-2x32, key = (0, 1) (jax.random.key(1)) ----------
__device__ __forceinline__ uint32_t rotl32(uint32_t x, int d) {
    return (x << d) | (x >> (32 - d));
}

__device__ __forceinline__ void threefry_key01(uint32_t x0, uint32_t x1,
                                               uint32_t& o0, uint32_t& o1) {
    const uint32_t ks0 = 0u;
    const uint32_t ks1 = 1u;
    const uint32_t ks2 = 0x1BD11BDBu;  // 0x1BD11BDA ^ 0 ^ 1
    x0 += ks0; x1 += ks1;
#define TF_RND(r) { x0 += x1; x1 = rotl32(x1, r); x1 ^= x0; }
    TF_RND(13) TF_RND(15) TF_RND(26) TF_RND(6)
    x0 += ks1; x1 += ks2 + 1u;
    TF_RND(17) TF_RND(29) TF_RND(16) TF_RND(24)
    x0 += ks2; x1 += ks0 + 2u;
    TF_RND(13) TF_RND(15) TF_RND(26) TF_RND(6)
    x0 += ks0; x1 += ks1 + 3u;
    TF_RND(17) TF_RND(29) TF_RND(16) TF_RND(24)
    x0 += ks1; x1 += ks2 + 4u;
    TF_RND(13) TF_RND(15) TF_RND(26) TF_RND(6)
    x0 += ks2; x1 += ks0 + 5u;
#undef TF_RND
    o0 = x0; o1 = x1;
}

// jax_threefry_partitionable=True (default since jax 0.4.36):
// bits[i] = x0 ^ x1 of threefry2x32(key, (i >> 32, i & 0xffffffff)).
__device__ __forceinline__ int explore_index(int i, int ne) {
    uint32_t o0, o1;
    threefry_key01(0u, (uint32_t)i, o0, o1);
    uint32_t bits = o0 ^ o1;
    float u = __uint_as_float((bits >> 9) | 0x3F800000u) - 1.0f;
    int t = (int)floorf(u * (float)ne);
    return min(t, ne - 1);
}

// ---------- kA: single-pass full-64-nb partial histograms (u8 fields) -----
// entry e = nb*400+u; word = e>>1; lo/hi 16b half per e; within a half:
// bits 0-7 = h0 (top0 count), bits 8-15 = h12 (top1+top2 count).
// Per-slab counts are tiny (lambda ~0.3), so u8 cannot overflow.
__global__ void k_histA(const int* __restrict__ top,
                        const int* __restrict__ nbid,
                        uint32_t* __restrict__ PA, int n, int chunk) {
    __shared__ uint32_t hist[HW_];
    for (int k = threadIdx.x; k < HW_; k += blockDim.x) hist[k] = 0u;
    __syncthreads();
    int lo = blockIdx.x * chunk, hi = min(n, lo + chunk);
    const int4* top4 = (const int4*)top;
#define PROC(nb, t0, t1, t2) { \
    int b_ = (nb) * N_UNITS; \
    int e0 = b_ + (t0), e1 = b_ + (t1), e2 = b_ + (t2); \
    atomicAdd(&hist[e0 >> 1], 1u << ((e0 & 1) * 16)); \
    atomicAdd(&hist[e1 >> 1], 0x100u << ((e1 & 1) * 16)); \
    atomicAdd(&hist[e2 >> 1], 0x100u << ((e2 & 1) * 16)); }
    for (int i0 = lo + threadIdx.x * 4; i0 < hi; i0 += blockDim.x * 4) {
        if (i0 + 4 <= hi) {
            int4 nb4 = *(const int4*)(nbid + i0);
            int j = (i0 * 3) >> 2;
            int4 ta = top4[j], tb = top4[j + 1], tc = top4[j + 2];
            PROC(nb4.x, ta.x, ta.y, ta.z)
            PROC(nb4.y, ta.w, tb.x, tb.y)
            PROC(nb4.z, tb.z, tb.w, tc.x)
            PROC(nb4.w, tc.y, tc.z, tc.w)
        } else {
            for (int i = i0; i < hi; ++i)
                PROC(nbid[i], top[3 * i], top[3 * i + 1], top[3 * i + 2])
        }
    }
#undef PROC
    __syncthreads();
    uint32_t* Pb = PA + (size_t)blockIdx.x * HW_;
    for (int k = threadIdx.x; k < HW_; k += blockDim.x) Pb[k] = hist[k];
}

// ---------- kR: wide reduce of PA slabs into 4 packed partials ------------
// R4[g][e] = h0_sum (lo16) | h12_sum (hi16) over slab group g.
__global__ void k_reduceA(const uint32_t* __restrict__ PA,
                          uint32_t* __restrict__ R4) {
    int idx = blockIdx.x * blockDim.x + threadIdx.x;   // 0 .. 4*HW_-1
    int w = idx % HW_;
    int g = idx / HW_;
    uint32_t h0a = 0, h12a = 0, h0b = 0, h12b = 0;
    const uint32_t* p = PA + (size_t)g * SLAB_PER_G * HW_ + w;
#pragma unroll 8
    for (int s = 0; s < SLAB_PER_G; ++s) {
        uint32_t v = p[(size_t)s * HW_];
        h0a  += v & 0xFFu;
        h12a += (v >> 8) & 0xFFu;
        h0b  += (v >> 16) & 0xFFu;
        h12b += v >> 24;
    }
    uint32_t* o = R4 + (size_t)g * NE_TOT;
    o[2 * w]     = h0a | (h12a << 16);
    o[2 * w + 1] = h0b | (h12b << 16);
}

// ---------- kB: fused final reduce + tables + base counts -----------------
__global__ void k_tables_base(const uint32_t* __restrict__ R4,
                              const int* __restrict__ usn,
                              int* __restrict__ wtbl,
                              int* __restrict__ wne,
                              float* __restrict__ out_counts) {
    __shared__ int scan[512];
    __shared__ int s_c[N_UNITS];
    int b = blockIdx.x;          // neighborhood id
    int u = threadIdx.x;
    int h0 = 0, h3 = 0;
    if (u < N_UNITS) {
        int e = b * N_UNITS + u;
        // packed u16-field add: per-field totals << 65536, no cross-carry
        uint32_t tot = R4[e] + R4[NE_TOT + e] + R4[2 * NE_TOT + e]
                     + R4[3 * NE_TOT + e];
        h0 = (int)(tot & 0xFFFFu);
        h3 = h0 + (int)(tot >> 16);
        s_c[u] = h3;              // top0 + top1/top2 contributions
    }
    int p = (u < N_UNITS && h0 > 0) ? 1 : 0;
    scan[u] = p;
    __syncthreads();
    for (int off = 1; off < 512; off <<= 1) {
        int add = (u >= off) ? scan[u - off] : 0;
        __syncthreads();
        scan[u] += add;
        __syncthreads();
    }
    if (p) wtbl[b * N_UNITS + scan[u] - 1] = u;
    if (u == 511) wne[b] = scan[511];
    if (u < N_UNITS && h3 > 0) {
        int2 nbr = ((const int2*)usn)[u];
        atomicAdd(&s_c[nbr.x], h3);
        atomicAdd(&s_c[nbr.y], h3);
    }
    __syncthreads();
    if (u < N_UNITS)
        out_counts[u * N_NEIGHB + b] = (float)s_c[u];
}

// ---------- k_main: candidates + scores + u8-packed explore LDS hist ------
// Per-256-spike tiles: int4-staged top loads; cand staged in LDS, dumped
// dense with float4; scores computed during the dump via s_ll gather.
// Explore hist: word = ex*16 + (nb>>2), byte field = nb&3 (max ~24/block).
__global__ void k_main(const float* __restrict__ logliks,
                       const int* __restrict__ top,
                       const int* __restrict__ usn,
                       const int* __restrict__ nbid,
                       const int* __restrict__ wtbl,
                       const int* __restrict__ wne,
                       uint32_t* __restrict__ PD,
                       float* __restrict__ out_cand,
                       float* __restrict__ out_scores,
                       int n, int chunk) {
    __shared__ uint32_t hist[EHW];
    __shared__ int   s_usn[N_UNITS * S];
    __shared__ float s_ll[N_UNITS];
    __shared__ int   s_ne[N_NEIGHB];
    __shared__ int   s_top[BS * 3];
    __shared__ float s_bc[BS * T];
    int tid = threadIdx.x;
    for (int k = tid; k < EHW; k += BS) hist[k] = 0u;
    for (int k = tid; k < N_UNITS * S; k += BS) s_usn[k] = usn[k];
    for (int k = tid; k < N_UNITS; k += BS)     s_ll[k]  = logliks[k];
    for (int k = tid; k < N_NEIGHB; k += BS)    s_ne[k]  = wne[k];
    __syncthreads();

    int lo = blockIdx.x * chunk, hi = min(n, lo + chunk);
    for (int t0 = lo; t0 < hi; t0 += BS) {
        int cnt = min(BS, hi - t0);
        // stage this tile's top rows (t0 is 256-aligned -> int4-safe)
        if (cnt == BS) {
            if (tid < (BS * 3) / 4)
                ((int4*)s_top)[tid] = ((const int4*)(top + (size_t)t0 * 3))[tid];
        } else {
            for (int k = tid; k < cnt * 3; k += BS)
                s_top[k] = top[(size_t)t0 * 3 + k];
        }
        __syncthreads();   // also guarantees prior tile's dump is complete

        int i = t0 + tid;
        if (i < hi) {
            int nb = nbid[i];
            int cand[T];
            cand[0] = s_top[tid * 3 + 0];
            cand[1] = s_top[tid * 3 + 1];
            cand[2] = s_top[tid * 3 + 2];
#pragma unroll
            for (int c = 0; c < C; ++c) {
                cand[C + 2 * c]     = s_usn[cand[c] * 2 + 0];
                cand[C + 2 * c + 1] = s_usn[cand[c] * 2 + 1];
            }
            int ne = s_ne[nb];
            if (ne > 0) {
                int t = explore_index(i, ne);
                int ex = wtbl[nb * N_UNITS + t];
                cand[T - 1] = ex;
                // explore tail-count (pre-dup), u8 field per nb
                atomicAdd(&hist[ex * 16 + (nb >> 2)], 1u << ((nb & 3) * 8));
            } else {
                cand[T - 1] = -1;
            }
#pragma unroll
            for (int jj = 0; jj < T; ++jj) {
                bool dup = false;
#pragma unroll
                for (int k = 0; k < jj; ++k) dup |= (cand[k] == cand[jj]);
                s_bc[tid * T + jj] = (float)(dup ? -1 : cand[jj]);
            }
        }
        __syncthreads();

        // dense coalesced dump; scores gathered from s_ll on the fly
        int nfloat = cnt * T;
        float* oc = out_cand   + (size_t)t0 * T;
        float* os = out_scores + (size_t)t0 * T;
        int nvec = nfloat & ~3;
        for (int e = tid * 4; e < nvec; e += BS * 4) {
            float4 v = *(const float4*)(s_bc + e);
            *(float4*)(oc + e) = v;
            float4 sc;
            int i0 = (int)v.x, i1 = (int)v.y, i2 = (int)v.z, i3 = (int)v.w;
            sc.x = (i0 >= 0) ? s_ll[i0] : 0.0f;
            sc.y = (i1 >= 0) ? s_ll[i1] : 0.0f;
            sc.z = (i2 >= 0) ? s_ll[i2] : 0.0f;
            sc.w = (i3 >= 0) ? s_ll[i3] : 0.0f;
            *(float4*)(os + e) = sc;
        }
        for (int e = nvec + tid; e < nfloat; e += BS) {
            float v = s_bc[e];
            oc[e] = v;
            int iv = (int)v;
            os[e] = (iv >= 0) ? s_ll[iv] : 0.0f;
        }
    }
    __syncthreads();
    uint32_t* Pb = PD + (size_t)blockIdx.x * EHW;
    for (int k = tid; k < EHW; k += BS) Pb[k] = hist[k];
}

// ---------- kF: reduce u8-packed explore partials into out_counts ---------
__global__ void k_finalE(const uint32_t* __restrict__ PD,
                         float* __restrict__ out_counts, int nslab) {
    __shared__ uint32_t red_e[256], red_o[256];
    int tid = threadIdx.x;
    int wl = tid & 63, g = tid >> 6;            // 4 slab groups
    int w = blockIdx.x * 64 + wl;               // word index in [0, EHW)
    int per = (nslab + 3) >> 2;
    int s0 = g * per, s1 = min(nslab, s0 + per);
    uint32_t acc_e = 0, acc_o = 0;              // u16 lanes: fields 0/2, 1/3
    for (int s = s0; s < s1; ++s) {
        uint32_t v = PD[(size_t)s * EHW + w];
        acc_e += v & 0x00FF00FFu;
        acc_o += (v >> 8) & 0x00FF00FFu;
    }
    red_e[tid] = acc_e;
    red_o[tid] = acc_o;
    __syncthreads();
    if (g == 0) {
        uint32_t e0 = red_e[wl], e1 = red_e[wl + 64],
                 e2 = red_e[wl + 128], e3 = red_e[wl + 192];
        uint32_t o0 = red_o[wl], o1 = red_o[wl + 64],
                 o2 = red_o[wl + 128], o3 = red_o[wl + 192];
        // unpack BEFORE combining groups (avoid u16-lane carry)
        uint32_t c0 = (e0 & 0xFFFFu) + (e1 & 0xFFFFu) + (e2 & 0xFFFFu) + (e3 & 0xFFFFu);
        uint32_t c2 = (e0 >> 16) + (e1 >> 16) + (e2 >> 16) + (e3 >> 16);
        uint32_t c1 = (o0 & 0xFFFFu) + (o1 & 0xFFFFu) + (o2 & 0xFFFFu) + (o3 & 0xFFFFu);
        uint32_t c3 = (o0 >> 16) + (o1 >> 16) + (o2 >> 16) + (o3 >> 16);
        int u = w >> 4, nb4 = (w & 15) * 4;
        float4* p = (float4*)(out_counts + u * N_NEIGHB + nb4);
        float4 v = *p;
        v.x += (float)c0;
        v.y += (float)c1;
        v.z += (float)c2;
        v.w += (float)c3;
        *p = v;
    }
}

extern "C" void kernel_launch(void* const* d_in, const int* in_sizes, int n_in,
                              void* d_out, int out_size, void* d_ws, size_t ws_size,
                              hipStream_t stream) {
    const float* logliks = (const float*)d_in[0];
    const int*   top     = (const int*)d_in[1];
    const int*   usn     = (const int*)d_in[2];
    const int*   nbid    = (const int*)d_in[3];

    int n = in_sizes[3];                                 // N_SPIKES
    int chunkA = ((n + NSLICE - 1) / NSLICE + 3) & ~3;   // mult of 4 (int4 path)
    int mb = (n + MCHUNK - 1) / MCHUNK;                  // 651 k_main blocks

    float* out        = (float*)d_out;
    float* out_cand   = out;
    float* out_counts = out + (size_t)n * T;
    float* out_scores = out_counts + (size_t)N_UNITS * N_NEIGHB;

    // Scratch in d_ws (~30.3 MB used):
    int*      wtbl = (int*)d_ws;                         // [64][400]
    int*      wne  = wtbl + N_NEIGHB * N_UNITS;          // [64]
    uint32_t* R4   = (uint32_t*)(wne + 64);              // 4*25600 = 409.6 KB
    uint32_t* PA   = R4 + (size_t)RGROUPS * NE_TOT;      // 256*12800 = 13.1 MB
    uint32_t* PD   = PA + (size_t)NSLICE * HW_;          // 651*6400 = 16.7 MB

    k_histA      <<<NSLICE, BS, 0, stream>>>(top, nbid, PA, n, chunkA);
    k_reduceA    <<<(RGROUPS * HW_) / BS, BS, 0, stream>>>(PA, R4);
    k_tables_base<<<N_NEIGHB, 512, 0, stream>>>(R4, usn, wtbl, wne, out_counts);
    k_main       <<<mb, BS, 0, stream>>>(logliks, top, usn, nbid, wtbl, wne,
                                         PD, out_cand, out_scores, n, MCHUNK);
    k_finalE     <<<EHW / 64, BS, 0, stream>>>(PD, out_counts, mb);
}

// Round 3
// 137.829 us; speedup vs baseline: 1.2508x; 1.1246x over previous
//
#include <hip/hip_runtime.h>
#include <stdint.h>

#define N_UNITS   400
#define N_NEIGHB  64
#define C         3
#define S         2
#define T         10      // C + C*S + E, E=1
#define NSLICE    256     // kA blocks / PA slabs
#define HW_       (N_NEIGHB * N_UNITS / 2)   // 12800 packed words (4 u8 fields each)
#define NE_TOT    (N_NEIGHB * N_UNITS)       // 25600 (nb,u) entries
#define RGROUPS   8
#define SLAB_PER_G (NSLICE / RGROUPS)        // 32
#define BS        256
#define BSA       1024                        // kA block size (4 waves/SIMD)
#define MCHUNK    1536                        // spikes per k_main block (6 tiles)
#define EHW       (N_UNITS * 16)              // 6400 u8x4-packed explore words

// ---------- JAX Threefry-2x32, key = (0, 1) (jax.random.key(1)) ----------
__device__ __forceinline__ uint32_t rotl32(uint32_t x, int d) {
    return (x << d) | (x >> (32 - d));
}

__device__ __forceinline__ void threefry_key01(uint32_t x0, uint32_t x1,
                                               uint32_t& o0, uint32_t& o1) {
    const uint32_t ks0 = 0u;
    const uint32_t ks1 = 1u;
    const uint32_t ks2 = 0x1BD11BDBu;  // 0x1BD11BDA ^ 0 ^ 1
    x0 += ks0; x1 += ks1;
#define TF_RND(r) { x0 += x1; x1 = rotl32(x1, r); x1 ^= x0; }
    TF_RND(13) TF_RND(15) TF_RND(26) TF_RND(6)
    x0 += ks1; x1 += ks2 + 1u;
    TF_RND(17) TF_RND(29) TF_RND(16) TF_RND(24)
    x0 += ks2; x1 += ks0 + 2u;
    TF_RND(13) TF_RND(15) TF_RND(26) TF_RND(6)
    x0 += ks0; x1 += ks1 + 3u;
    TF_RND(17) TF_RND(29) TF_RND(16) TF_RND(24)
    x0 += ks1; x1 += ks2 + 4u;
    TF_RND(13) TF_RND(15) TF_RND(26) TF_RND(6)
    x0 += ks2; x1 += ks0 + 5u;
#undef TF_RND
    o0 = x0; o1 = x1;
}

// jax_threefry_partitionable=True (default since jax 0.4.36):
// bits[i] = x0 ^ x1 of threefry2x32(key, (i >> 32, i & 0xffffffff)).
__device__ __forceinline__ int explore_index(int i, int ne) {
    uint32_t o0, o1;
    threefry_key01(0u, (uint32_t)i, o0, o1);
    uint32_t bits = o0 ^ o1;
    float u = __uint_as_float((bits >> 9) | 0x3F800000u) - 1.0f;
    int t = (int)floorf(u * (float)ne);
    return min(t, ne - 1);
}

// ---------- kA: single-pass full-64-nb partial histograms (u8 fields) -----
// entry e = nb*400+u; word = e>>1; lo/hi 16b half per e; within a half:
// bits 0-7 = h0 (top0 count), bits 8-15 = h12 (top1+top2 count).
// Per-slab counts are tiny (lambda ~0.3), so u8 cannot overflow.
// 1024 threads/block: 4 waves/SIMD (was 1 -> pure HBM-latency exposure).
__global__ void k_histA(const int* __restrict__ top,
                        const int* __restrict__ nbid,
                        uint32_t* __restrict__ PA, int n, int chunk) {
    __shared__ uint32_t hist[HW_];
    for (int k = threadIdx.x; k < HW_; k += blockDim.x) hist[k] = 0u;
    __syncthreads();
    int lo = blockIdx.x * chunk, hi = min(n, lo + chunk);
    const int4* top4 = (const int4*)top;
#define PROC(nb, t0, t1, t2) { \
    int b_ = (nb) * N_UNITS; \
    int e0 = b_ + (t0), e1 = b_ + (t1), e2 = b_ + (t2); \
    atomicAdd(&hist[e0 >> 1], 1u << ((e0 & 1) * 16)); \
    atomicAdd(&hist[e1 >> 1], 0x100u << ((e1 & 1) * 16)); \
    atomicAdd(&hist[e2 >> 1], 0x100u << ((e2 & 1) * 16)); }
    for (int i0 = lo + threadIdx.x * 4; i0 < hi; i0 += blockDim.x * 4) {
        if (i0 + 4 <= hi) {
            int4 nb4 = *(const int4*)(nbid + i0);
            int j = (i0 * 3) >> 2;
            int4 ta = top4[j], tb = top4[j + 1], tc = top4[j + 2];
            PROC(nb4.x, ta.x, ta.y, ta.z)
            PROC(nb4.y, ta.w, tb.x, tb.y)
            PROC(nb4.z, tb.z, tb.w, tc.x)
            PROC(nb4.w, tc.y, tc.z, tc.w)
        } else {
            for (int i = i0; i < hi; ++i)
                PROC(nbid[i], top[3 * i], top[3 * i + 1], top[3 * i + 2])
        }
    }
#undef PROC
    __syncthreads();
    uint32_t* Pb = PA + (size_t)blockIdx.x * HW_;
    for (int k = threadIdx.x; k < HW_; k += blockDim.x) Pb[k] = hist[k];
}

// ---------- kR: wide reduce of PA slabs into 8 packed partials ------------
// R8[g][e] = h0_sum (lo16) | h12_sum (hi16) over slab group g.
__global__ void k_reduceA(const uint32_t* __restrict__ PA,
                          uint32_t* __restrict__ R8) {
    int idx = blockIdx.x * blockDim.x + threadIdx.x;   // 0 .. 8*HW_-1
    int w = idx % HW_;
    int g = idx / HW_;
    uint32_t h0a = 0, h12a = 0, h0b = 0, h12b = 0;
    const uint32_t* p = PA + (size_t)g * SLAB_PER_G * HW_ + w;
#pragma unroll 8
    for (int s = 0; s < SLAB_PER_G; ++s) {
        uint32_t v = p[(size_t)s * HW_];
        h0a  += v & 0xFFu;
        h12a += (v >> 8) & 0xFFu;
        h0b  += (v >> 16) & 0xFFu;
        h12b += v >> 24;
    }
    uint32_t* o = R8 + (size_t)g * NE_TOT;
    o[2 * w]     = h0a | (h12a << 16);
    o[2 * w + 1] = h0b | (h12b << 16);
}

// ---------- kB: ballot-scan tables + base counts (2 barriers) -------------
__global__ void k_tables_base(const uint32_t* __restrict__ R8,
                              const int* __restrict__ usn,
                              int* __restrict__ wtbl,
                              int* __restrict__ wne,
                              float* __restrict__ out_counts) {
    __shared__ int s_c[N_UNITS];
    __shared__ int wsum[8];
    int b = blockIdx.x;          // neighborhood id
    int u = threadIdx.x;         // 512 threads = 8 waves
    int h0 = 0, h3 = 0;
    if (u < N_UNITS) {
        int e = b * N_UNITS + u;
        // packed u16-field add: per-field totals << 65536, no cross-carry
        uint32_t tot = 0;
#pragma unroll
        for (int g = 0; g < RGROUPS; ++g) tot += R8[g * NE_TOT + e];
        h0 = (int)(tot & 0xFFFFu);
        h3 = h0 + (int)(tot >> 16);
        s_c[u] = h3;              // top0 + top1/top2 contributions
    }
    bool p = (u < N_UNITS) && (h0 > 0);
    unsigned long long m = __ballot(p);
    int lane = u & 63, wid = u >> 6;
    if (lane == 0) wsum[wid] = __popcll(m);
    int lp = __popcll(m & ((1ull << lane) - 1ull));
    __syncthreads();              // covers s_c and wsum
    int off = 0;
    for (int w2 = 0; w2 < wid; ++w2) off += wsum[w2];
    if (p) wtbl[b * N_UNITS + off + lp] = u;   // ascending unit order kept
    if (u == 0) {
        int tot = 0;
        for (int w2 = 0; w2 < 8; ++w2) tot += wsum[w2];
        wne[b] = tot;
    }
    if (u < N_UNITS && h3 > 0) {
        int2 nbr = ((const int2*)usn)[u];
        atomicAdd(&s_c[nbr.x], h3);
        atomicAdd(&s_c[nbr.y], h3);
    }
    __syncthreads();
    if (u < N_UNITS)
        out_counts[u * N_NEIGHB + b] = (float)s_c[u];
}

// ---------- k_main: candidates + scores + u8-packed explore LDS hist ------
// Per-256-spike tiles: int4-staged top loads; cand staged in LDS, dumped
// dense with float4; scores computed during the dump via s_ll gather.
// Explore hist: word = ex*16 + (nb>>2), byte field = nb&3 (max ~24/block).
__global__ void k_main(const float* __restrict__ logliks,
                       const int* __restrict__ top,
                       const int* __restrict__ usn,
                       const int* __restrict__ nbid,
                       const int* __restrict__ wtbl,
                       const int* __restrict__ wne,
                       uint32_t* __restrict__ PD,
                       float* __restrict__ out_cand,
                       float* __restrict__ out_scores,
                       int n, int chunk) {
    __shared__ uint32_t hist[EHW];
    __shared__ int   s_usn[N_UNITS * S];
    __shared__ float s_ll[N_UNITS];
    __shared__ int   s_ne[N_NEIGHB];
    __shared__ int   s_top[BS * 3];
    __shared__ float s_bc[BS * T];
    int tid = threadIdx.x;
    for (int k = tid; k < EHW; k += BS) hist[k] = 0u;
    for (int k = tid; k < N_UNITS * S; k += BS) s_usn[k] = usn[k];
    for (int k = tid; k < N_UNITS; k += BS)     s_ll[k]  = logliks[k];
    for (int k = tid; k < N_NEIGHB; k += BS)    s_ne[k]  = wne[k];
    __syncthreads();

    int lo = blockIdx.x * chunk, hi = min(n, lo + chunk);
    for (int t0 = lo; t0 < hi; t0 += BS) {
        int cnt = min(BS, hi - t0);
        // stage this tile's top rows (t0 is 256-aligned -> int4-safe)
        if (cnt == BS) {
            if (tid < (BS * 3) / 4)
                ((int4*)s_top)[tid] = ((const int4*)(top + (size_t)t0 * 3))[tid];
        } else {
            for (int k = tid; k < cnt * 3; k += BS)
                s_top[k] = top[(size_t)t0 * 3 + k];
        }
        __syncthreads();   // also guarantees prior tile's dump is complete

        int i = t0 + tid;
        if (i < hi) {
            int nb = nbid[i];
            int cand[T];
            cand[0] = s_top[tid * 3 + 0];
            cand[1] = s_top[tid * 3 + 1];
            cand[2] = s_top[tid * 3 + 2];
#pragma unroll
            for (int c = 0; c < C; ++c) {
                cand[C + 2 * c]     = s_usn[cand[c] * 2 + 0];
                cand[C + 2 * c + 1] = s_usn[cand[c] * 2 + 1];
            }
            int ne = s_ne[nb];
            if (ne > 0) {
                int t = explore_index(i, ne);
                int ex = wtbl[nb * N_UNITS + t];
                cand[T - 1] = ex;
                // explore tail-count (pre-dup), u8 field per nb
                atomicAdd(&hist[ex * 16 + (nb >> 2)], 1u << ((nb & 3) * 8));
            } else {
                cand[T - 1] = -1;
            }
#pragma unroll
            for (int jj = 0; jj < T; ++jj) {
                bool dup = false;
#pragma unroll
                for (int k = 0; k < jj; ++k) dup |= (cand[k] == cand[jj]);
                s_bc[tid * T + jj] = (float)(dup ? -1 : cand[jj]);
            }
        }
        __syncthreads();

        // dense coalesced dump; scores gathered from s_ll on the fly
        int nfloat = cnt * T;
        float* oc = out_cand   + (size_t)t0 * T;
        float* os = out_scores + (size_t)t0 * T;
        int nvec = nfloat & ~3;
        for (int e = tid * 4; e < nvec; e += BS * 4) {
            float4 v = *(const float4*)(s_bc + e);
            *(float4*)(oc + e) = v;
            float4 sc;
            int i0 = (int)v.x, i1 = (int)v.y, i2 = (int)v.z, i3 = (int)v.w;
            sc.x = (i0 >= 0) ? s_ll[i0] : 0.0f;
            sc.y = (i1 >= 0) ? s_ll[i1] : 0.0f;
            sc.z = (i2 >= 0) ? s_ll[i2] : 0.0f;
            sc.w = (i3 >= 0) ? s_ll[i3] : 0.0f;
            *(float4*)(os + e) = sc;
        }
        for (int e = nvec + tid; e < nfloat; e += BS) {
            float v = s_bc[e];
            oc[e] = v;
            int iv = (int)v;
            os[e] = (iv >= 0) ? s_ll[iv] : 0.0f;
        }
    }
    __syncthreads();
    uint32_t* Pb = PD + (size_t)blockIdx.x * EHW;
    for (int k = tid; k < EHW; k += BS) Pb[k] = hist[k];
}

// ---------- kF: reduce u8-packed explore partials into out_counts ---------
// 200 blocks: 32 words x 8 slab-groups each.
__global__ void k_finalE(const uint32_t* __restrict__ PD,
                         float* __restrict__ out_counts, int nslab) {
    __shared__ uint32_t red_e[256], red_o[256];
    int tid = threadIdx.x;
    int wl = tid & 31, g = tid >> 5;            // 8 slab groups
    int w = blockIdx.x * 32 + wl;               // word index in [0, EHW)
    int per = (nslab + 7) >> 3;
    int s0 = g * per, s1 = min(nslab, s0 + per);
    uint32_t acc_e = 0, acc_o = 0;              // u16 lanes: fields 0/2, 1/3
    for (int s = s0; s < s1; ++s) {
        uint32_t v = PD[(size_t)s * EHW + w];
        acc_e += v & 0x00FF00FFu;
        acc_o += (v >> 8) & 0x00FF00FFu;
    }
    red_e[tid] = acc_e;
    red_o[tid] = acc_o;
    __syncthreads();
    if (g == 0) {
        // unpack BEFORE combining groups (avoid u16-lane carry)
        uint32_t c0 = 0, c1 = 0, c2 = 0, c3 = 0;
#pragma unroll
        for (int k = 0; k < 8; ++k) {
            uint32_t e = red_e[wl + 32 * k], o = red_o[wl + 32 * k];
            c0 += e & 0xFFFFu;  c2 += e >> 16;
            c1 += o & 0xFFFFu;  c3 += o >> 16;
        }
        int u = w >> 4, nb4 = (w & 15) * 4;
        float4* p = (float4*)(out_counts + u * N_NEIGHB + nb4);
        float4 v = *p;
        v.x += (float)c0;
        v.y += (float)c1;
        v.z += (float)c2;
        v.w += (float)c3;
        *p = v;
    }
}

extern "C" void kernel_launch(void* const* d_in, const int* in_sizes, int n_in,
                              void* d_out, int out_size, void* d_ws, size_t ws_size,
                              hipStream_t stream) {
    const float* logliks = (const float*)d_in[0];
    const int*   top     = (const int*)d_in[1];
    const int*   usn     = (const int*)d_in[2];
    const int*   nbid    = (const int*)d_in[3];

    int n = in_sizes[3];                                 // N_SPIKES
    int chunkA = ((n + NSLICE - 1) / NSLICE + 3) & ~3;   // mult of 4 (int4 path)
    int mb = (n + MCHUNK - 1) / MCHUNK;                  // 651 k_main blocks

    float* out        = (float*)d_out;
    float* out_cand   = out;
    float* out_counts = out + (size_t)n * T;
    float* out_scores = out_counts + (size_t)N_UNITS * N_NEIGHB;

    // Scratch in d_ws (~30.7 MB used):
    int*      wtbl = (int*)d_ws;                         // [64][400]
    int*      wne  = wtbl + N_NEIGHB * N_UNITS;          // [64]
    uint32_t* R8   = (uint32_t*)(wne + 64);              // 8*25600 = 819.2 KB
    uint32_t* PA   = R8 + (size_t)RGROUPS * NE_TOT;      // 256*12800 = 13.1 MB
    uint32_t* PD   = PA + (size_t)NSLICE * HW_;          // 651*6400 = 16.7 MB

    k_histA      <<<NSLICE, BSA, 0, stream>>>(top, nbid, PA, n, chunkA);
    k_reduceA    <<<(RGROUPS * HW_) / BS, BS, 0, stream>>>(PA, R8);
    k_tables_base<<<N_NEIGHB, 512, 0, stream>>>(R8, usn, wtbl, wne, out_counts);
    k_main       <<<mb, BS, 0, stream>>>(logliks, top, usn, nbid, wtbl, wne,
                                         PD, out_cand, out_scores, n, MCHUNK);
    k_finalE     <<<EHW / 32, BS, 0, stream>>>(PD, out_counts, mb);
}